// Round 3
// baseline (472.435 us; speedup 1.0000x reference)
//
#include <hip/hip_runtime.h>
#include <stdint.h>

#define H100 100
#define T64  64
#define NB   128
#define DLAG 10

// ---- workspace layout (uint32 offsets) ----
#define OFF_HH0T 0          // [2][15000] hh0 packed, layout [(k4*300+j)*2+p]
#define OFF_IH1  30000      // [2][15000] ih1 row-packed [j*50+k2]
#define OFF_HH1  60000      // [2][15000] hh1 row-packed [j*50+k2]
#define OFF_CTX  90000      // [10000]  ctx packed k-major [k2*100+o]
#define OFF_AWC  100000     // [50]     attn_w[0][100:200] packed
#define OFF_OW   100050     // [2][50]  out_w halves packed
#define OFF_P    100152     // float [2][128][64] partial readouts

typedef _Float16 half2_t __attribute__((ext_vector_type(2)));
typedef __fp16   pk16x2  __attribute__((ext_vector_type(2)));

__device__ __forceinline__ float fdot2u(uint32_t a, uint32_t b, float c) {
#if __has_builtin(__builtin_amdgcn_fdot2)
    return __builtin_amdgcn_fdot2(__builtin_bit_cast(half2_t, a),
                                  __builtin_bit_cast(half2_t, b), c, false);
#else
    half2_t ha = __builtin_bit_cast(half2_t, a), hb = __builtin_bit_cast(half2_t, b);
    return c + (float)ha[0]*(float)hb[0] + (float)ha[1]*(float)hb[1];
#endif
}
__device__ __forceinline__ uint32_t pkrtz(float a, float b) {
    pk16x2 h = __builtin_amdgcn_cvt_pkrtz(a, b);
    return __builtin_bit_cast(uint32_t, h);
}
__device__ __forceinline__ uint32_t pk_rn(float a, float b) {
    half2_t h; h[0] = (_Float16)a; h[1] = (_Float16)b;
    return __builtin_bit_cast(uint32_t, h);
}
__device__ __forceinline__ float lo16(uint32_t u){ return (float)__builtin_bit_cast(half2_t,u)[0]; }
__device__ __forceinline__ float hi16(uint32_t u){ return (float)__builtin_bit_cast(half2_t,u)[1]; }
__device__ __forceinline__ float sigm(float x){ return 1.f/(1.f+__expf(-x)); }
__device__ __forceinline__ float tanhfast(float x){ return 1.f - 2.f/(1.f+__expf(2.f*x)); }
__device__ __forceinline__ float gru_el(float pr, float pz, float gin, float ghn, float hp) {
    float r = sigm(pr), z = sigm(pz);
    float n = tanhfast(gin + r*ghn);
    return (1.f - z)*n + z*hp;
}

struct SMem {
    uint32_t hh0[15000];        // f16-pair weights, conflict-free k-major-by-2
    uint32_t ctx[10000];        // f16-pair, k-major
    uint32_t cache[2][T64][50]; // raw hiddens, f16 pairs
    float    sv[2][T64];        // s[t'] = dot(attn_wc, cache[t'])
    float    g[400];            // gate pre-activations: [0:200]=r,z sums; [200:300]=gi_n; [300:400]=gh_n
    uint32_t h0c[50];           // carry (mixed) hidden, layer0, f16 pairs
    uint32_t h1c[50];
    uint32_t hn0[50];           // raw GRU outputs
    uint32_t hn1[50];
    uint32_t cpk[2][50];        // attention context c, packed
    float    hmix0[100];
    float    hmix1[100];
    float    x[T64*3];
    float    ih0f[900];
};

// ---------------- prep: pack weights to f16 pairs ----------------
__global__ void prep_pack(const float* __restrict__ w1hh0, const float* __restrict__ w2hh0,
                          const float* __restrict__ w1ih1, const float* __restrict__ w2ih1,
                          const float* __restrict__ w1hh1, const float* __restrict__ w2hh1,
                          const float* __restrict__ attw,  const float* __restrict__ ctxw,
                          const float* __restrict__ outw,  uint32_t* __restrict__ ws) {
    int g = blockIdx.x*blockDim.x + threadIdx.x;
    if (g < 30000) {
        int br = g/15000, idx = g%15000;
        int kj = idx>>1, p = idx&1;
        int k4 = kj/300, j = kj%300;
        const float* w = br ? w2hh0 : w1hh0;
        int c = j*H100 + 4*k4 + 2*p;
        ws[OFF_HH0T + g] = pk_rn(w[c], w[c+1]);
    } else if (g < 60000) {
        int t2 = g-30000; int br = t2/15000, idx = t2%15000;
        int j = idx/50, k2 = idx%50;
        const float* w = br ? w2ih1 : w1ih1;
        ws[OFF_IH1 + t2] = pk_rn(w[j*H100+2*k2], w[j*H100+2*k2+1]);
    } else if (g < 90000) {
        int t2 = g-60000; int br = t2/15000, idx = t2%15000;
        int j = idx/50, k2 = idx%50;
        const float* w = br ? w2hh1 : w1hh1;
        ws[OFF_HH1 + t2] = pk_rn(w[j*H100+2*k2], w[j*H100+2*k2+1]);
    } else if (g < 100000) {
        int idx = g-90000; int k2 = idx/100, o = idx%100;
        ws[OFF_CTX + idx] = pk_rn(ctxw[o*200+2*k2], ctxw[o*200+2*k2+1]);
    } else if (g < 100050) {
        int i2 = g-100000;
        ws[OFF_AWC + i2] = pk_rn(attw[100+2*i2], attw[101+2*i2]);
    } else if (g < 100150) {
        int t2 = g-100050; int br = t2/50, i2 = t2%50;
        ws[OFF_OW + t2] = pk_rn(outw[br*H100+2*i2], outw[br*H100+2*i2+1]);
    }
}

// ---------------- main: one block per (branch, batch) chain ----------------
__global__ __launch_bounds__(512, 2)
void gru_seq(const float* __restrict__ recv,
             const float* __restrict__ ih0_1, const float* __restrict__ bih0_1,
             const float* __restrict__ bhh0_1, const float* __restrict__ bih1_1,
             const float* __restrict__ bhh1_1,
             const float* __restrict__ ih0_2, const float* __restrict__ bih0_2,
             const float* __restrict__ bhh0_2, const float* __restrict__ bih1_2,
             const float* __restrict__ bhh1_2,
             const float* __restrict__ ctxb,
             uint32_t* __restrict__ ws) {
    extern __shared__ uint32_t smem_raw[];
    SMem* S = (SMem*)smem_raw;
    const int tid = threadIdx.x;
    const int br  = blockIdx.x >> 7;
    const int b   = blockIdx.x & 127;

    const float* ih0 = br ? ih0_2  : ih0_1;
    const float* bi0 = br ? bih0_2 : bih0_1;
    const float* bh0 = br ? bhh0_2 : bhh0_1;
    const float* bi1 = br ? bih1_2 : bih1_1;
    const float* bh1 = br ? bhh1_2 : bhh1_1;

    // cooperative LDS staging (once per launch)
    const uint32_t* whh0 = ws + OFF_HH0T + br*15000;
    for (int i = tid; i < 15000; i += 512) S->hh0[i] = whh0[i];
    for (int i = tid; i < 10000; i += 512) S->ctx[i] = ws[OFF_CTX + i];
    for (int i = tid; i < T64*3; i += 512) S->x[i]   = recv[b*T64*3 + i];
    for (int i = tid; i < 900;   i += 512) S->ih0f[i] = ih0[i];
    if (tid < 128) S->sv[tid>>6][tid&63] = 0.f;
    if (tid < 100) { int l = tid/50; S->cache[l][0][tid%50] = 0u; }
    if (tid < 50)  { S->h0c[tid] = 0u; S->h1c[tid] = 0u; }

    // per-thread register-resident weights
    uint32_t rih1[50], rhh1[50];
    float rbi0=0.f, rbh0=0.f, rbi1=0.f, rbh1=0.f;
    if (tid < 300) {
        const uint32_t* pih1 = ws + OFF_IH1 + br*15000 + tid*50;
        const uint32_t* phh1 = ws + OFF_HH1 + br*15000 + tid*50;
        #pragma unroll
        for (int k = 0; k < 50; ++k) { rih1[k] = pih1[k]; rhh1[k] = phh1[k]; }
        rbi0 = bi0[tid]; rbh0 = bh0[tid]; rbi1 = bi1[tid]; rbh1 = bh1[tid];
    }
    float rctxb = (tid < 100) ? ctxb[tid] : 0.f;
    uint32_t rawc = 0u, rowp = 0u;
    {
        int la = tid - 320;
        if (la >= 0 && la < 50) rawc = ws[OFF_AWC + la];
        int lb = tid - 384;
        if (lb >= 0 && lb < 50) rowp = ws[OFF_OW + br*50 + lb];
    }
    float* p_out = (float*)(ws + OFF_P);
    __syncthreads();

    float gh1save = 0.f;

    for (int t = 0; t < T64; ++t) {
        const int m = (t > 1) ? t : 1;    // attention span = max(t,1)
        // ---- PHASE A: layer0 gates + gh1 (reg) ; attention softmax+c for both layers ----
        if (tid < 300) {
            const int j = tid;
            float x0 = S->x[t*3], x1 = S->x[t*3+1], x2 = S->x[t*3+2];
            float accI = rbi0 + S->ih0f[j*3]*x0 + S->ih0f[j*3+1]*x1 + S->ih0f[j*3+2]*x2;
            float acc0 = rbh0;
            float acc1 = rbh1;
            #pragma unroll
            for (int k4 = 0; k4 < 25; ++k4) {
                uint2 w   = *(const uint2*)&S->hh0[(k4*300 + j)*2];
                uint2 h0p = *(const uint2*)&S->h0c[2*k4];
                uint2 h1p = *(const uint2*)&S->h1c[2*k4];
                acc0 = fdot2u(w.x, h0p.x, acc0);
                acc0 = fdot2u(w.y, h0p.y, acc0);
                acc1 = fdot2u(rhh1[2*k4],   h1p.x, acc1);
                acc1 = fdot2u(rhh1[2*k4+1], h1p.y, acc1);
            }
            if (j < 200) S->g[j] = accI + acc0;
            else { S->g[j] = accI; S->g[j+100] = acc0; }
            gh1save = acc1;
        } else if (tid >= 320 && tid < 448) {
            const int l  = (tid < 384) ? 0 : 1;
            const int la = (tid - 320) & 63;
            // softmax over s-values (hn-dot + bias cancel by shift invariance)
            float sval = (la < m) ? S->sv[l][la] : -3e38f;
            float mx = sval;
            #pragma unroll
            for (int off = 32; off; off >>= 1) mx = fmaxf(mx, __shfl_xor(mx, off));
            float p = (la < m) ? __expf(sval - mx) : 0.f;
            float ssum = p;
            #pragma unroll
            for (int off = 32; off; off >>= 1) ssum += __shfl_xor(ssum, off);
            float a = p / ssum;
            // c = sum_t' a[t'] * cache[t']  (lanes <50 own h-pairs)
            float c0 = 0.f, c1 = 0.f;
            int hsel = (la < 50) ? la : 0;
            for (int tp = 0; tp < m; ++tp) {
                float av = __shfl(a, tp);
                uint32_t u = S->cache[l][tp][hsel];
                c0 += av * lo16(u);
                c1 += av * hi16(u);
            }
            if (la < 50) S->cpk[l][la] = pkrtz(c0, c1);
        }
        __syncthreads();
        // ---- PHASE B: combine layer0 -> hn0 ----
        if (tid < 50) {
            int e0 = 2*tid, e1 = e0+1;
            uint32_t hp = S->h0c[tid];
            float h0 = gru_el(S->g[e0], S->g[100+e0], S->g[200+e0], S->g[300+e0], lo16(hp));
            float h1 = gru_el(S->g[e1], S->g[100+e1], S->g[200+e1], S->g[300+e1], hi16(hp));
            S->hn0[tid] = pkrtz(h0, h1);
        }
        __syncthreads();
        // ---- PHASE C: gi1 (reg weights) + stash; s0[t] + cache0[t] ----
        if (tid < 300) {
            const int j = tid;
            float acc = rbi1;
            #pragma unroll
            for (int k4 = 0; k4 < 25; ++k4) {
                uint2 hp = *(const uint2*)&S->hn0[2*k4];
                acc = fdot2u(rih1[2*k4],   hp.x, acc);
                acc = fdot2u(rih1[2*k4+1], hp.y, acc);
            }
            if (j < 200) S->g[j] = acc + gh1save;
            else { S->g[j] = acc; S->g[j+100] = gh1save; }
        } else if (tid >= 320 && tid < 384) {
            int la = tid - 320;
            float v = (la < 50) ? fdot2u(rawc, S->hn0[la], 0.f) : 0.f;
            #pragma unroll
            for (int off = 32; off; off >>= 1) v += __shfl_xor(v, off);
            if (la == 0) S->sv[0][t] = v;
            if (la < 50) S->cache[0][t][la] = S->hn0[la];
        }
        __syncthreads();
        // ---- PHASE D: combine layer1 -> hn1 ----
        if (tid < 50) {
            int e0 = 2*tid, e1 = e0+1;
            uint32_t hp = S->h1c[tid];
            float h0 = gru_el(S->g[e0], S->g[100+e0], S->g[200+e0], S->g[300+e0], lo16(hp));
            float h1 = gru_el(S->g[e1], S->g[100+e1], S->g[200+e1], S->g[300+e1], hi16(hp));
            S->hn1[tid] = pkrtz(h0, h1);
        }
        __syncthreads();
        // ---- PHASE E: ctx mix (both layers) ; s1[t]+cache1[t] ; readout partial ----
        if (tid < 100) {
            const int o = tid;
            float a0 = rctxb, a1 = rctxb;
            #pragma unroll
            for (int k2 = 0; k2 < 50; ++k2) {
                uint32_t w = S->ctx[k2*100 + o];
                a0 = fdot2u(w, S->cpk[0][k2], a0);
                a1 = fdot2u(w, S->cpk[1][k2], a1);
            }
            #pragma unroll
            for (int k2 = 0; k2 < 50; ++k2) {
                uint32_t w = S->ctx[(50+k2)*100 + o];
                a0 = fdot2u(w, S->hn0[k2], a0);
                a1 = fdot2u(w, S->hn1[k2], a1);
            }
            S->hmix0[o] = a0;
            S->hmix1[o] = a1;
        } else if (tid >= 320 && tid < 384) {
            int la = tid - 320;
            float v = (la < 50) ? fdot2u(rawc, S->hn1[la], 0.f) : 0.f;
            #pragma unroll
            for (int off = 32; off; off >>= 1) v += __shfl_xor(v, off);
            if (la == 0) S->sv[1][t] = v;
            if (la < 50) S->cache[1][t][la] = S->hn1[la];
        } else if (tid >= 384 && tid < 448) {
            int lb = tid - 384;
            float v = (lb < 50) ? fdot2u(rowp, S->hn1[lb], 0.f) : 0.f;
            #pragma unroll
            for (int off = 32; off; off >>= 1) v += __shfl_xor(v, off);
            if (lb == 0) p_out[br*8192 + b*64 + t] = v;
        }
        __syncthreads();
        // ---- PHASE F: carry update (t==0 keeps raw hn) ----
        if (tid < 50) {
            if (t == 0) { S->h0c[tid] = S->hn0[tid]; S->h1c[tid] = S->hn1[tid]; }
            else {
                S->h0c[tid] = pkrtz(S->hmix0[2*tid], S->hmix0[2*tid+1]);
                S->h1c[tid] = pkrtz(S->hmix1[2*tid], S->hmix1[2*tid+1]);
            }
        }
        __syncthreads();
    }
}

// ---------------- final: pair partials across branches, sigmoid ----------------
__global__ void fin_out(const uint32_t* __restrict__ ws, const float* __restrict__ outb,
                        float* __restrict__ out) {
    int i = blockIdx.x*blockDim.x + threadIdx.x;
    if (i >= NB*T64) return;
    int b = i >> 6, t = i & 63;
    const float* p = (const float*)(ws + OFF_P);
    int t2 = t + DLAG; if (t2 > T64-1) t2 = T64-1;
    float logit = p[0*8192 + b*64 + t] + p[1*8192 + b*64 + t2] + outb[0];
    out[i] = 1.f/(1.f+__expf(-logit));
}

extern "C" void kernel_launch(void* const* d_in, const int* in_sizes, int n_in,
                              void* d_out, int out_size, void* d_ws, size_t ws_size,
                              hipStream_t stream) {
    const float* recv   = (const float*)d_in[0];
    const float* w1ih0  = (const float*)d_in[1];
    const float* w1hh0  = (const float*)d_in[2];
    const float* w1bih0 = (const float*)d_in[3];
    const float* w1bhh0 = (const float*)d_in[4];
    const float* w1ih1  = (const float*)d_in[5];
    const float* w1hh1  = (const float*)d_in[6];
    const float* w1bih1 = (const float*)d_in[7];
    const float* w1bhh1 = (const float*)d_in[8];
    const float* w2ih0  = (const float*)d_in[9];
    const float* w2hh0  = (const float*)d_in[10];
    const float* w2bih0 = (const float*)d_in[11];
    const float* w2bhh0 = (const float*)d_in[12];
    const float* w2ih1  = (const float*)d_in[13];
    const float* w2hh1  = (const float*)d_in[14];
    const float* w2bih1 = (const float*)d_in[15];
    const float* w2bhh1 = (const float*)d_in[16];
    const float* attw   = (const float*)d_in[17];
    const float* ctxw   = (const float*)d_in[19];
    const float* ctxb   = (const float*)d_in[20];
    const float* outw   = (const float*)d_in[21];
    const float* outb   = (const float*)d_in[22];
    uint32_t* ws = (uint32_t*)d_ws;
    float* out = (float*)d_out;

    (void)hipFuncSetAttribute((const void*)gru_seq, hipFuncAttributeMaxDynamicSharedMemorySize,
                              (int)sizeof(SMem));

    prep_pack<<<(100150 + 255)/256, 256, 0, stream>>>(
        w1hh0, w2hh0, w1ih1, w2ih1, w1hh1, w2hh1, attw, ctxw, outw, ws);

    gru_seq<<<256, 512, sizeof(SMem), stream>>>(
        recv,
        w1ih0, w1bih0, w1bhh0, w1bih1, w1bhh1,
        w2ih0, w2bih0, w2bhh0, w2bih1, w2bhh1,
        ctxb, ws);

    fin_out<<<(NB*T64 + 255)/256, 256, 0, stream>>>(ws, outb, out);
}

// Round 4
// 263.690 us; speedup vs baseline: 1.7916x; 1.7916x over previous
//
#include <hip/hip_runtime.h>
#include <stdint.h>

#define H100 100
#define T64  64
#define NB   128
#define DLAG 10

// ---- workspace layout (uint32 offsets) ----
#define OFF_HH0 0          // [2][300][50] hh0 row-pair-packed
#define OFF_IH1 30000      // [2][300][50]
#define OFF_HH1 60000      // [2][300][50]
#define OFF_CTX 90000      // [100][100]  ctx row-pair-packed (o-major)
#define OFF_AWC 100000     // [50] attn_w[0][100:200] pairs
#define OFF_OW  100050     // [2][50] out_w halves pairs
#define OFF_P   100152     // float [2][128][64] partial readouts

typedef _Float16 half2_t __attribute__((ext_vector_type(2)));
typedef __fp16   pk16x2  __attribute__((ext_vector_type(2)));

__device__ __forceinline__ float fdot2u(uint32_t a, uint32_t b, float c) {
#if __has_builtin(__builtin_amdgcn_fdot2)
    return __builtin_amdgcn_fdot2(__builtin_bit_cast(half2_t, a),
                                  __builtin_bit_cast(half2_t, b), c, false);
#else
    half2_t ha = __builtin_bit_cast(half2_t, a), hb = __builtin_bit_cast(half2_t, b);
    return c + (float)ha[0]*(float)hb[0] + (float)ha[1]*(float)hb[1];
#endif
}
__device__ __forceinline__ uint32_t pkrtz(float a, float b) {
    pk16x2 h = __builtin_amdgcn_cvt_pkrtz(a, b);
    return __builtin_bit_cast(uint32_t, h);
}
__device__ __forceinline__ uint32_t pk_rn(float a, float b) {
    half2_t h; h[0] = (_Float16)a; h[1] = (_Float16)b;
    return __builtin_bit_cast(uint32_t, h);
}
__device__ __forceinline__ float lo16(uint32_t u){ return (float)__builtin_bit_cast(half2_t,u)[0]; }
__device__ __forceinline__ float hi16(uint32_t u){ return (float)__builtin_bit_cast(half2_t,u)[1]; }
__device__ __forceinline__ float sigm(float x){ return 1.f/(1.f+__expf(-x)); }
__device__ __forceinline__ float tanhfast(float x){ return 1.f - 2.f/(1.f+__expf(2.f*x)); }
__device__ __forceinline__ float gru_el(float pr, float pz, float gin, float ghn, float hp) {
    float r = sigm(pr), z = sigm(pz);
    float n = tanhfast(gin + r*ghn);
    return (1.f - z)*n + z*hp;
}
__device__ __forceinline__ float wsum(float v){
    #pragma unroll
    for (int off = 32; off; off >>= 1) v += __shfl_xor(v, off);
    return v;
}
__device__ __forceinline__ float wmax(float v){
    #pragma unroll
    for (int off = 32; off; off >>= 1) v = fmaxf(v, __shfl_xor(v, off));
    return v;
}
__device__ __forceinline__ uint32_t rlane(uint32_t v, int lane){
    return (uint32_t)__builtin_amdgcn_readlane((int)v, lane);
}

struct SMem {
    alignas(16) uint32_t cache_t[2][50][66];  // transposed hidden cache, pad 66
    alignas(16) float grz1[200];
    alignas(16) float gin1[100];
    alignas(16) float ghn1[100];
    alignas(16) float grz2[200];
    alignas(16) float gin2[100];
    alignas(16) float ghn2[100];
    alignas(16) float sv[2][64];
    alignas(16) float atile[2][64];
    alignas(16) uint32_t cpkq[2][64];         // attention context, f16 pairs
    alignas(16) float hmix0[104];
    alignas(16) float hmix1[104];
    alignas(16) float x[192];
};

// ---------------- prep: pack weights to f16 pairs ----------------
__global__ void prep_pack(const float* __restrict__ w1hh0, const float* __restrict__ w2hh0,
                          const float* __restrict__ w1ih1, const float* __restrict__ w2ih1,
                          const float* __restrict__ w1hh1, const float* __restrict__ w2hh1,
                          const float* __restrict__ attw,  const float* __restrict__ ctxw,
                          const float* __restrict__ outw,  uint32_t* __restrict__ ws) {
    int g = blockIdx.x*blockDim.x + threadIdx.x;
    if (g < 30000) {
        int br = g/15000, idx = g%15000;
        int j = idx/50, kp = idx%50;
        const float* w = br ? w2hh0 : w1hh0;
        ws[OFF_HH0 + g] = pk_rn(w[j*H100+2*kp], w[j*H100+2*kp+1]);
    } else if (g < 60000) {
        int t2 = g-30000; int br = t2/15000, idx = t2%15000;
        int j = idx/50, kp = idx%50;
        const float* w = br ? w2ih1 : w1ih1;
        ws[OFF_IH1 + t2] = pk_rn(w[j*H100+2*kp], w[j*H100+2*kp+1]);
    } else if (g < 90000) {
        int t2 = g-60000; int br = t2/15000, idx = t2%15000;
        int j = idx/50, kp = idx%50;
        const float* w = br ? w2hh1 : w1hh1;
        ws[OFF_HH1 + t2] = pk_rn(w[j*H100+2*kp], w[j*H100+2*kp+1]);
    } else if (g < 100000) {
        int idx = g-90000; int o = idx/100, kp = idx%100;
        ws[OFF_CTX + idx] = pk_rn(ctxw[o*200+2*kp], ctxw[o*200+2*kp+1]);
    } else if (g < 100050) {
        int i2 = g-100000;
        ws[OFF_AWC + i2] = pk_rn(attw[100+2*i2], attw[101+2*i2]);
    } else if (g < 100150) {
        int t2 = g-100050; int br = t2/50, i2 = t2%50;
        ws[OFF_OW + t2] = pk_rn(outw[br*H100+2*i2], outw[br*H100+2*i2+1]);
    }
}

// ---------------- main: one block per (branch, batch) chain ----------------
__global__ __launch_bounds__(512, 2)
void gru_seq(const float* __restrict__ recv,
             const float* __restrict__ ih0_1, const float* __restrict__ bih0_1,
             const float* __restrict__ bhh0_1, const float* __restrict__ bih1_1,
             const float* __restrict__ bhh1_1,
             const float* __restrict__ ih0_2, const float* __restrict__ bih0_2,
             const float* __restrict__ bhh0_2, const float* __restrict__ bih1_2,
             const float* __restrict__ bhh1_2,
             const float* __restrict__ ctxb,
             uint32_t* __restrict__ ws) {
    __shared__ SMem S;
    const int tid = threadIdx.x;
    const int w   = tid >> 6;
    const int la  = tid & 63;
    const int br  = blockIdx.x >> 7;
    const int b   = blockIdx.x & 127;

    const float* ih0 = br ? ih0_2  : ih0_1;
    const float* bi0 = br ? bih0_2 : bih0_1;
    const float* bh0 = br ? bhh0_2 : bhh0_1;
    const float* bi1 = br ? bih1_2 : bih1_1;
    const float* bh1 = br ? bhh1_2 : bhh1_1;

    // staging + init
    for (int i = tid; i < 192; i += 512) S.x[i] = recv[b*192 + i];
    for (int i = tid; i < 2*50*66; i += 512) ((uint32_t*)S.cache_t)[i] = 0u;
    if (tid < 128) S.sv[tid>>6][tid&63] = 0.f;

    // role-overlaid register file
    uint32_t wreg[150];
    float fb0=0.f, fb1=0.f, fb2=0.f, fb3=0.f;
    float rix0=0.f, rix1=0.f, rix2=0.f;
    if (tid < 300) {
        const uint32_t* p0 = ws + OFF_HH0 + br*15000 + tid*50;
        const uint32_t* p1 = ws + OFF_HH1 + br*15000 + tid*50;
        const uint32_t* p2 = ws + OFF_IH1 + br*15000 + tid*50;
        #pragma unroll
        for (int k = 0; k < 50; ++k) { wreg[k] = p0[k]; wreg[50+k] = p1[k]; wreg[100+k] = p2[k]; }
        fb0 = bi0[tid]; fb1 = bh0[tid]; fb2 = bi1[tid]; fb3 = bh1[tid];
        rix0 = ih0[tid*3]; rix1 = ih0[tid*3+1]; rix2 = ih0[tid*3+2];
    } else if (tid < 400) {
        const int o = tid - 300;
        const uint32_t* pc = ws + OFF_CTX + o*100;
        #pragma unroll
        for (int k = 0; k < 100; ++k) wreg[k] = pc[k];
        fb0 = ctxb[o];
    }
    uint32_t rawc = 0u, rowp = 0u;
    if (w == 0 && la < 50) rawc = ws[OFF_AWC + la];
    if (w == 7 && la < 50) rowp = ws[OFF_OW + br*50 + la];
    float* p_out = (float*)(ws + OFF_P);

    uint32_t hn0p = 0u, hn1p = 0u, h0cp = 0u, h1cp = 0u;
    float gh1save = 0.f;
    __syncthreads();

    for (int t = 0; t < T64; ++t) {
        // ================= P1: carry-combine (all) | gates (w0-4) | attn (w5,6) | readout (w7) =====
        if (la < 50) {
            if (t == 0)      { h0cp = 0u;   h1cp = 0u;   }
            else if (t == 1) { h0cp = hn0p; h1cp = hn1p; }
            else {
                float2 a0 = *(const float2*)&S.hmix0[2*la];
                float2 a1 = *(const float2*)&S.hmix1[2*la];
                h0cp = pkrtz(a0.x, a0.y);
                h1cp = pkrtz(a1.x, a1.y);
            }
        }
        if (tid < 300) {
            float x0 = S.x[3*t], x1 = S.x[3*t+1], x2 = S.x[3*t+2];
            float accI = fb0 + rix0*x0 + rix1*x1 + rix2*x2;
            float a0a = 0.f, a0b = 0.f;
            #pragma unroll
            for (int k = 0; k < 50; k += 2) {
                a0a = fdot2u(wreg[k],   rlane(h0cp, k),   a0a);
                a0b = fdot2u(wreg[k+1], rlane(h0cp, k+1), a0b);
            }
            float a1a = 0.f, a1b = 0.f;
            #pragma unroll
            for (int k = 0; k < 50; k += 2) {
                a1a = fdot2u(wreg[50+k],   rlane(h1cp, k),   a1a);
                a1b = fdot2u(wreg[50+k+1], rlane(h1cp, k+1), a1b);
            }
            float acc0 = fb1 + a0a + a0b;
            gh1save = fb3 + a1a + a1b;
            if (tid < 200) S.grz1[tid] = accI + acc0;
            else { S.gin1[tid-200] = accI; S.ghn1[tid-200] = acc0; }
        } else if (w == 5 || w == 6) {
            const int l = w - 5;
            const int m = (t > 1) ? t : 1;
            float sval = S.sv[l][la];
            float sv2  = (la < m) ? sval : -3e38f;
            float mx   = wmax(sv2);
            float p    = (la < m) ? __expf(sv2 - mx) : 0.f;
            float ssum = wsum(p);
            S.atile[l][la] = p;
            if (la < 50) {
                float c0 = 0.f, c1 = 0.f;
                const uint32_t* crow = &S.cache_t[l][la][0];
                const int np = (m + 1) >> 1;
                for (int tp = 0; tp < np; ++tp) {
                    float2 ap = *(const float2*)&S.atile[l][2*tp];
                    uint2  cp = *(const uint2*)&crow[2*tp];
                    c0 += ap.x*lo16(cp.x) + ap.y*lo16(cp.y);
                    c1 += ap.x*hi16(cp.x) + ap.y*hi16(cp.y);
                }
                float inv = 1.f/ssum;
                S.cpkq[l][la] = pkrtz(c0*inv, c1*inv);
            }
        } else if (w == 7 && t > 0) {
            float v = (la < 50) ? fdot2u(rowp, hn1p, 0.f) : 0.f;
            v = wsum(v);
            if (la == 0) p_out[br*8192 + b*64 + (t-1)] = v;
        }
        __syncthreads();
        // ================= P2: hn0 (all waves) ; s0/cache0 (w0) ; gi1 (w0-4) =====
        if (la < 50) {
            float2 pr = *(const float2*)&S.grz1[2*la];
            float2 pz = *(const float2*)&S.grz1[100+2*la];
            float2 gi = *(const float2*)&S.gin1[2*la];
            float2 gh = *(const float2*)&S.ghn1[2*la];
            float h0 = gru_el(pr.x, pz.x, gi.x, gh.x, lo16(h0cp));
            float h1 = gru_el(pr.y, pz.y, gi.y, gh.y, hi16(h0cp));
            hn0p = pkrtz(h0, h1);
        }
        if (w == 0) {
            float v = (la < 50) ? fdot2u(rawc, hn0p, 0.f) : 0.f;
            v = wsum(v);
            if (la == 0) S.sv[0][t] = v;
            if (la < 50) S.cache_t[0][la][t] = hn0p;
        }
        if (tid < 300) {
            float ga = 0.f, gb = 0.f;
            #pragma unroll
            for (int k = 0; k < 50; k += 2) {
                ga = fdot2u(wreg[100+k],   rlane(hn0p, k),   ga);
                gb = fdot2u(wreg[100+k+1], rlane(hn0p, k+1), gb);
            }
            float gi1 = fb2 + ga + gb;
            if (tid < 200) S.grz2[tid] = gi1 + gh1save;
            else { S.gin2[tid-200] = gi1; S.ghn2[tid-200] = gh1save; }
        }
        __syncthreads();
        // ================= P3: hn1 (all) ; s1/cache1 (w0) ; ctx-mix (tid 300-399) =====
        if (la < 50) {
            float2 pr = *(const float2*)&S.grz2[2*la];
            float2 pz = *(const float2*)&S.grz2[100+2*la];
            float2 gi = *(const float2*)&S.gin2[2*la];
            float2 gh = *(const float2*)&S.ghn2[2*la];
            float h0 = gru_el(pr.x, pz.x, gi.x, gh.x, lo16(h1cp));
            float h1 = gru_el(pr.y, pz.y, gi.y, gh.y, hi16(h1cp));
            hn1p = pkrtz(h0, h1);
        }
        if (w == 0) {
            float v = (la < 50) ? fdot2u(rawc, hn1p, 0.f) : 0.f;
            v = wsum(v);
            if (la == 0) S.sv[1][t] = v;
            if (la < 50) S.cache_t[1][la][t] = hn1p;
        }
        if (tid >= 300 && tid < 400) {
            const int o = tid - 300;
            float p0 = fb0, p1 = fb0;
            #pragma unroll
            for (int kb = 0; kb < 13; ++kb) {
                uint4 v0 = *(const uint4*)&S.cpkq[0][kb*4];
                uint4 v1 = *(const uint4*)&S.cpkq[1][kb*4];
                #pragma unroll
                for (int i = 0; i < 4; ++i) {
                    const int k = kb*4 + i;
                    if (k < 50) {
                        uint32_t e0 = (i==0)?v0.x:(i==1)?v0.y:(i==2)?v0.z:v0.w;
                        uint32_t e1 = (i==0)?v1.x:(i==1)?v1.y:(i==2)?v1.z:v1.w;
                        p0 = fdot2u(wreg[k], e0, p0);
                        p1 = fdot2u(wreg[k], e1, p1);
                    }
                }
            }
            #pragma unroll
            for (int k = 0; k < 50; ++k) {
                p0 = fdot2u(wreg[50+k], rlane(hn0p, k), p0);
                p1 = fdot2u(wreg[50+k], rlane(hn1p, k), p1);
            }
            S.hmix0[o] = p0; S.hmix1[o] = p1;
        }
        __syncthreads();
    }
    // epilogue: readout for t = 63
    if (w == 7) {
        float v = (la < 50) ? fdot2u(rowp, hn1p, 0.f) : 0.f;
        v = wsum(v);
        if (la == 0) p_out[br*8192 + b*64 + 63] = v;
    }
}

// ---------------- final: pair partials across branches, sigmoid ----------------
__global__ void fin_out(const uint32_t* __restrict__ ws, const float* __restrict__ outb,
                        float* __restrict__ out) {
    int i = blockIdx.x*blockDim.x + threadIdx.x;
    if (i >= NB*T64) return;
    int b = i >> 6, t = i & 63;
    const float* p = (const float*)(ws + OFF_P);
    int t2 = t + DLAG; if (t2 > T64-1) t2 = T64-1;
    float logit = p[0*8192 + b*64 + t] + p[1*8192 + b*64 + t2] + outb[0];
    out[i] = 1.f/(1.f+__expf(-logit));
}

extern "C" void kernel_launch(void* const* d_in, const int* in_sizes, int n_in,
                              void* d_out, int out_size, void* d_ws, size_t ws_size,
                              hipStream_t stream) {
    const float* recv   = (const float*)d_in[0];
    const float* w1ih0  = (const float*)d_in[1];
    const float* w1hh0  = (const float*)d_in[2];
    const float* w1bih0 = (const float*)d_in[3];
    const float* w1bhh0 = (const float*)d_in[4];
    const float* w1ih1  = (const float*)d_in[5];
    const float* w1hh1  = (const float*)d_in[6];
    const float* w1bih1 = (const float*)d_in[7];
    const float* w1bhh1 = (const float*)d_in[8];
    const float* w2ih0  = (const float*)d_in[9];
    const float* w2hh0  = (const float*)d_in[10];
    const float* w2bih0 = (const float*)d_in[11];
    const float* w2bhh0 = (const float*)d_in[12];
    const float* w2ih1  = (const float*)d_in[13];
    const float* w2hh1  = (const float*)d_in[14];
    const float* w2bih1 = (const float*)d_in[15];
    const float* w2bhh1 = (const float*)d_in[16];
    const float* attw   = (const float*)d_in[17];
    const float* ctxw   = (const float*)d_in[19];
    const float* ctxb   = (const float*)d_in[20];
    const float* outw   = (const float*)d_in[21];
    const float* outb   = (const float*)d_in[22];
    uint32_t* ws = (uint32_t*)d_ws;
    float* out = (float*)d_out;

    prep_pack<<<(100150 + 255)/256, 256, 0, stream>>>(
        w1hh0, w2hh0, w1ih1, w2ih1, w1hh1, w2hh1, attw, ctxw, outw, ws);

    gru_seq<<<256, 512, 0, stream>>>(
        recv,
        w1ih0, w1bih0, w1bhh0, w1bih1, w1bhh1,
        w2ih0, w2bih0, w2bhh0, w2bih1, w2bhh1,
        ctxb, ws);

    fin_out<<<(NB*T64 + 255)/256, 256, 0, stream>>>(ws, outb, out);
}